// Round 21
// baseline (328.216 us; speedup 1.0000x reference)
//
#include <hip/hip_runtime.h>
#include <cmath>

namespace {

constexpr int XC = 64, XH = 128, XW = 128;
constexpr int NSEQ = 128;   // B(2) * 64 cubes
constexpr int TLEN = 1025;  // gt token + 1024
constexpr int LSEQ = 1024;
constexpr int TT = 96;      // token tile for fused p1
constexpr int NT = 11;      // ceil(1025/96)

struct MP {
    const float *in_w, *conv_w, *conv_b, *xproj_w, *dt_w, *dt_b, *A_log, *D, *out_w;
};

__device__ __forceinline__ int xidx(int b, int c, int h, int w) {
    return ((b * XC + c) * XH + h) * XW + w;
}
__device__ __forceinline__ int oidx(int b, int cube, int c, int i, int j) {
    int h = cube * 2 + (i >> 3);
    int w = ((i & 7) << 4) | j;
    return xidx(b, c, h, w);
}
__device__ __forceinline__ float siluf(float v) { return v / (1.0f + __expf(-v)); }
__device__ __forceinline__ float softplusf(float v) {
    return v > 20.0f ? v : log1pf(__expf(v));
}

template <int MODE>
__device__ __forceinline__ float gather_val(const float* __restrict__ x,
                                            const float* __restrict__ s_gt,
                                            int t, int k, int b, int bi, int bj) {
    if (t == 0) return s_gt[k];
    int l = t - 1;
    if (MODE == 0) {
        int i2 = l >> 5, j2 = l & 31;
        int h = bi * 16 + (i2 >> 1), w = bj * 16 + (j2 >> 1);
        int coff = ((i2 & 1) << 1) | (j2 & 1);
        return x[xidx(b, k * 4 + coff, h, w)];
    } else if (MODE == 1) {
        int c = l >> 4, j = l & 15;
        return x[xidx(b, c, bi * 16 + k, bj * 16 + j)];
    } else {
        int c = l >> 4, i = l & 15;
        return x[xidx(b, c, bi * 16 + i, bj * 16 + k)];
    }
}
__device__ __forceinline__ float gather_rt(int mode, const float* __restrict__ x,
                                           const float* __restrict__ s_gt,
                                           int t, int k, int b, int bi, int bj) {
    if (mode == 0) return gather_val<0>(x, s_gt, t, k, b, bi, bj);
    if (mode == 1) return gather_val<1>(x, s_gt, t, k, b, bi, bj);
    return gather_val<2>(x, s_gt, t, k, b, bi, bj);
}

// ==== phase 1: gather+LN+in-proj(xi)+conv+x-proj; LN output v -> VB =========
template <int MODE_C>
__global__ __launch_bounds__(256) void k_p1(
    const float* __restrict__ x,
    const float* __restrict__ gt1, const float* __restrict__ gt2,
    const float* __restrict__ ln1g, const float* __restrict__ ln1b,
    const float* __restrict__ ln2g, const float* __restrict__ ln2b,
    MP P0, MP P1, int mode_base,
    float* __restrict__ VB0, float* __restrict__ SC0, size_t arena)
{
    const int mode = (MODE_C >= 0) ? MODE_C : (mode_base + (int)blockIdx.y);
    const MP P = (mode == 0) ? P0 : P1;
    const float* gt  = (mode == 0) ? gt1 : gt2;
    const float* lng = (mode == 0) ? ln1g : ln2g;
    const float* lnb = (mode == 0) ? ln1b : ln2b;
    float* VB = VB0 + (size_t)blockIdx.y * arena;
    float* sc = SC0 + (size_t)blockIdx.y * arena;

    const int n = blockIdx.x / NT, tile = blockIdx.x % NT;
    const int t0 = tile * TT;
    const int ntk = min(TT, TLEN - t0);
    const int nth = ntk + 3;  // with 3-token front halo
    const int b = n >> 6, cube = n & 63, bi = cube >> 3, bj = cube & 7;
    const int tid = threadIdx.x;

    __shared__ __align__(16) float s_pool[TT * 37];
    float (*s_v)[17]  = (float(*)[17])s_pool;
    float (*s_xc)[37] = (float(*)[37])s_pool;
    __shared__ __align__(16) float s_xi[TT + 3][36];
    __shared__ __align__(16) float s_wT[16][32];   // in_w rows 0..31 transposed
    __shared__ __align__(16) float s_xpT[32][36];  // s_xpT[cc][q] = xproj_w[q+1][cc]
    __shared__ float s_xp0[32];
    __shared__ float s_cw[128], s_cb[32], s_dw[32], s_db[32];
    __shared__ float s_g[16], s_bb[16], s_gt[16];
    __shared__ float s_dt0[TT];

    for (int i = tid; i < 32 * 16; i += 256) s_wT[i & 15][i >> 4] = P.in_w[i];
    for (int i = tid; i < 33 * 32; i += 256) {
        int r = i >> 5, cc = i & 31;
        float v = P.xproj_w[i];
        if (r == 0) s_xp0[cc] = v;
        else s_xpT[cc][r - 1] = v;
    }
    if (tid < 128) s_cw[tid] = P.conv_w[tid];
    if (tid < 32) { s_cb[tid] = P.conv_b[tid]; s_dw[tid] = P.dt_w[tid]; s_db[tid] = P.dt_b[tid]; }
    if (tid < 16) { s_g[tid] = lng[tid]; s_bb[tid] = lnb[tid]; s_gt[tid] = gt[tid]; }
    __syncthreads();

    // ---- gather, element-per-thread
    for (int it = tid; it < nth * 16; it += 256) {
        int tl = it >> 4, k = it & 15;
        int t = t0 - 3 + tl;
        float v;
        if (t < 0) v = 0.f;
        else if (MODE_C >= 0) v = gather_val<(MODE_C >= 0 ? MODE_C : 0)>(x, s_gt, t, k, b, bi, bj);
        else v = gather_rt(mode, x, s_gt, t, k, b, bi, bj);
        s_v[tl][k] = v;
    }
    __syncthreads();

    // ---- layernorm, token-per-thread from LDS
    for (int tl = tid; tl < nth; tl += 256) {
        int t = t0 - 3 + tl;
        if (t < 0) continue;
        float v[16], mu = 0.f;
#pragma unroll
        for (int k = 0; k < 16; k++) { v[k] = s_v[tl][k]; mu += v[k]; }
        mu *= (1.f / 16.f);
        float var = 0.f;
#pragma unroll
        for (int k = 0; k < 16; k++) { float d = v[k] - mu; var += d * d; }
        float inv = rsqrtf(var * (1.f / 16.f) + 1e-5f);
#pragma unroll
        for (int k = 0; k < 16; k++) s_v[tl][k] = (v[k] - mu) * inv * s_g[k] + s_bb[k];
    }
    __syncthreads();

    // ---- VB store (LN output) + in-proj xi half, 4tok x 4oc tiles
    {
        float* vb = VB + ((size_t)n * TLEN + t0) * 16;
        for (int it = tid; it < ntk * 16; it += 256) {
            int j = it >> 4, k = it & 15;
            vb[it] = s_v[j + 3][k];
        }
        const int ntt = (nth + 3) >> 2;
        for (int tl0 = tid; tl0 < ntt * 8; tl0 += 256) {
            int tt = tl0 >> 3, og = tl0 & 7;
            int oc = og * 4;
            float acc[4][4] = {{0.f}};
#pragma unroll
            for (int k = 0; k < 16; k++) {
                float4 wv = *(const float4*)&s_wT[k][oc];
                float a0 = s_v[4 * tt + 0][k];
                float a1 = s_v[4 * tt + 1][k];
                float a2 = s_v[4 * tt + 2][k];
                float a3 = s_v[4 * tt + 3][k];
                acc[0][0] += a0 * wv.x; acc[0][1] += a0 * wv.y; acc[0][2] += a0 * wv.z; acc[0][3] += a0 * wv.w;
                acc[1][0] += a1 * wv.x; acc[1][1] += a1 * wv.y; acc[1][2] += a1 * wv.z; acc[1][3] += a1 * wv.w;
                acc[2][0] += a2 * wv.x; acc[2][1] += a2 * wv.y; acc[2][2] += a2 * wv.z; acc[2][3] += a2 * wv.w;
                acc[3][0] += a3 * wv.x; acc[3][1] += a3 * wv.y; acc[3][2] += a3 * wv.z; acc[3][3] += a3 * wv.w;
            }
#pragma unroll
            for (int i = 0; i < 4; i++) {
                int tl = 4 * tt + i;
                if (tl >= nth) break;
                *(float4*)&s_xi[tl][oc] =
                    make_float4(acc[i][0], acc[i][1], acc[i][2], acc[i][3]);
            }
        }
    }
    __syncthreads();  // s_v dead; pool becomes s_xc

    // ---- conv4 + silu; emit xc to global inline
    {
        int cc = tid & 31, jg = tid >> 5;
        float c0 = s_cw[cc * 4 + 0], c1 = s_cw[cc * 4 + 1];
        float c2 = s_cw[cc * 4 + 2], c3 = s_cw[cc * 4 + 3];
        float cb = s_cb[cc];
        float* scb = sc + ((size_t)n * TLEN + t0) * 96;
        for (int j = jg; j < ntk; j += 8) {
            float acc = 0.f;
            acc += c0 * s_xi[j + 0][cc];
            acc += c1 * s_xi[j + 1][cc];
            acc += c2 * s_xi[j + 2][cc];
            acc += c3 * s_xi[j + 3][cc];
            float v = siluf(acc + cb);
            s_xc[j][cc] = v;
            scb[j * 96 + cc] = v;
        }
    }
    __syncthreads();

    // ---- x-proj B/C rows, 4-token x 4-q register tile
    {
        int qt = tid & 7, tt = tid >> 3;
        if (4 * tt < ntk) {
            float acc[4][4] = {{0.f}};
#pragma unroll
            for (int cc = 0; cc < 32; cc++) {
                float4 wv = *(const float4*)&s_xpT[cc][4 * qt];
                float a0 = s_xc[4 * tt + 0][cc];
                float a1 = s_xc[4 * tt + 1][cc];
                float a2 = s_xc[4 * tt + 2][cc];
                float a3 = s_xc[4 * tt + 3][cc];
                acc[0][0] += a0 * wv.x; acc[0][1] += a0 * wv.y; acc[0][2] += a0 * wv.z; acc[0][3] += a0 * wv.w;
                acc[1][0] += a1 * wv.x; acc[1][1] += a1 * wv.y; acc[1][2] += a1 * wv.z; acc[1][3] += a1 * wv.w;
                acc[2][0] += a2 * wv.x; acc[2][1] += a2 * wv.y; acc[2][2] += a2 * wv.z; acc[2][3] += a2 * wv.w;
                acc[3][0] += a3 * wv.x; acc[3][1] += a3 * wv.y; acc[3][2] += a3 * wv.z; acc[3][3] += a3 * wv.w;
            }
#pragma unroll
            for (int i = 0; i < 4; i++) {
                int j = 4 * tt + i;
                if (j < ntk)
                    *(float4*)&sc[((size_t)n * TLEN + t0 + j) * 96 + 64 + 4 * qt] =
                        make_float4(acc[i][0], acc[i][1], acc[i][2], acc[i][3]);
            }
        }
        if (tid < ntk) {
            float acc = 0.f;
#pragma unroll
            for (int cc = 0; cc < 32; cc++) acc += s_xc[tid][cc] * s_xp0[cc];
            s_dt0[tid] = acc;
        }
    }
    __syncthreads();

    // ---- dt block emit
    {
        float* scb = sc + ((size_t)n * TLEN + t0) * 96;
        for (int it = tid; it < ntk * 32; it += 256) {
            int j = it >> 5, d = it & 31;
            scb[j * 96 + 32 + d] = softplusf(s_dt0[j] * s_dw[d] + s_db[d]);
        }
    }
}

// -------- phase 2a: per-chunk scan summaries; stage only xc/dt/B (80 f) -----
template <int MODE_C, int CHUNKT, int NCHT>
__global__ __launch_bounds__(128) void k_scan1(
    const float* __restrict__ SC0, MP P0, MP P1, int mode_base,
    float* __restrict__ PS0, float* __restrict__ FS0, size_t arena)
{
    const int mode = (MODE_C >= 0) ? MODE_C : (mode_base + (int)blockIdx.y);
    const float* A_log = (mode == 0) ? P0.A_log : P1.A_log;
    const float* sc = SC0 + (size_t)blockIdx.y * arena;
    float* Psum = PS0 + (size_t)blockIdx.y * arena;
    float* Fsum = FS0 + (size_t)blockIdx.y * arena;

    int n = blockIdx.x / NCHT;
    int c = blockIdx.x % NCHT;
    int t0 = c * CHUNKT;
    int nt = min(CHUNKT, TLEN - t0);
    __shared__ __align__(16) float s_sc[CHUNKT * 80];   // xc[32] dt[32] B[16]
    const float* src = sc + ((size_t)n * TLEN + t0) * 96;
    for (int i = threadIdx.x; i < nt * 20; i += 128) {
        int row = i / 20, q = i - row * 20;
        ((float4*)s_sc)[row * 20 + q] = *(const float4*)&src[row * 96 + q * 4];
    }
    int tid = threadIdx.x, d = tid >> 2, sg = tid & 3;
    float4 Av = *(const float4*)&A_log[d * 16 + sg * 4];
    float A0 = -__expf(Av.x), A1 = -__expf(Av.y), A2 = -__expf(Av.z), A3 = -__expf(Av.w);
    __syncthreads();
    float h0 = 0.f, h1 = 0.f, h2 = 0.f, h3 = 0.f;
    float P0v = 1.f, P1v = 1.f, P2v = 1.f, P3v = 1.f;
    for (int t = 0; t < nt; t++) {
        const float* p = s_sc + t * 80;
        float dt = p[32 + d], xc = p[d];
        float4 Bv = *(const float4*)&p[64 + sg * 4];
        float a0 = __expf(dt * A0); h0 = a0 * h0 + dt * Bv.x * xc; P0v *= a0;
        float a1 = __expf(dt * A1); h1 = a1 * h1 + dt * Bv.y * xc; P1v *= a1;
        float a2 = __expf(dt * A2); h2 = a2 * h2 + dt * Bv.z * xc; P2v *= a2;
        float a3 = __expf(dt * A3); h3 = a3 * h3 + dt * Bv.w * xc; P3v *= a3;
    }
    size_t base = ((size_t)n * NCHT + c) * 512 + d * 16 + sg * 4;
    *(float4*)&Psum[base] = make_float4(P0v, P1v, P2v, P3v);
    *(float4*)&Fsum[base] = make_float4(h0, h1, h2, h3);
}

// -------- phase 2b: combine chunk summaries -> incoming state per chunk -----
template <int NCHT>
__global__ __launch_bounds__(512) void k_comb(
    const float* __restrict__ PS0, const float* __restrict__ FS0,
    float* __restrict__ HI0, size_t arena)
{
    const float* Psum = PS0 + (size_t)blockIdx.y * arena;
    const float* Fsum = FS0 + (size_t)blockIdx.y * arena;
    float* Hin = HI0 + (size_t)blockIdx.y * arena;
    int n = blockIdx.x, tid = threadIdx.x;
    const float* pb = Psum + (size_t)n * NCHT * 512;
    const float* fb = Fsum + (size_t)n * NCHT * 512;
    float* hb = Hin + (size_t)n * NCHT * 512;
    float H = 0.f;
#pragma unroll
    for (int c = 0; c < NCHT; c++) {
        float P = pb[(size_t)c * 512 + tid];
        float F = fb[(size_t)c * 512 + tid];
        hb[(size_t)c * 512 + tid] = H;
        H = F + P * H;
    }
}

// --- phase 2c: scan pass 2 + GATE; gated y written over SC's xc slot --------
template <int MODE_C, int CHUNKT, int NCHT>
__global__ __launch_bounds__(128) void k_scan2(
    float* __restrict__ SC0, const float* __restrict__ VB0,
    MP P0, MP P1, int mode_base,
    const float* __restrict__ HI0, size_t arena)
{
    const int mode = (MODE_C >= 0) ? MODE_C : (mode_base + (int)blockIdx.y);
    const MP P = (mode == 0) ? P0 : P1;
    const float* A_log = P.A_log;
    const float* Dp = P.D;
    float* sc = SC0 + (size_t)blockIdx.y * arena;
    const float* VB = VB0 + (size_t)blockIdx.y * arena;
    const float* Hin = HI0 + (size_t)blockIdx.y * arena;

    int n = blockIdx.x / NCHT;
    int c = blockIdx.x % NCHT;
    int t0 = c * CHUNKT;
    int nt = min(CHUNKT, TLEN - t0);
    __shared__ __align__(16) float s_sc[CHUNKT * 96];
    __shared__ __align__(16) float s_val[CHUNKT][17];
    __shared__ float s_wz[16][32];   // s_wz[k][cc] = in_w[(32+cc)*16+k]
    const float* src = sc + ((size_t)n * TLEN + t0) * 96;
    int nv4 = nt * 24;
    for (int i = threadIdx.x; i < nv4; i += 128)
        ((float4*)s_sc)[i] = ((const float4*)src)[i];
    {
        const float* vbp = VB + ((size_t)n * TLEN + t0) * 16;
        for (int i = threadIdx.x; i < nt * 16; i += 128)
            s_val[i >> 4][i & 15] = vbp[i];
        for (int i = threadIdx.x; i < 512; i += 128) {
            int cc = i >> 4, k = i & 15;
            s_wz[k][cc] = P.in_w[(32 + cc) * 16 + k];
        }
    }
    int tid = threadIdx.x, d = tid >> 2, sg = tid & 3;
    float4 Av = *(const float4*)&A_log[d * 16 + sg * 4];
    float A0 = -__expf(Av.x), A1 = -__expf(Av.y), A2 = -__expf(Av.z), A3 = -__expf(Av.w);
    float Dd = Dp[d];
    float4 Hv = *(const float4*)&Hin[((size_t)n * NCHT + c) * 512 + d * 16 + sg * 4];
    float h0 = Hv.x, h1 = Hv.y, h2 = Hv.z, h3 = Hv.w;
    __syncthreads();
    // y[t][d] overwrites s_sc[t*96+d] after xc[t][d]'s final read (wave-local)
    for (int t = 0; t < nt; t++) {
        float* p = s_sc + t * 96;
        float dt = p[32 + d], xc = p[d];
        float4 Bv = *(const float4*)&p[64 + sg * 4];
        float4 Cv = *(const float4*)&p[80 + sg * 4];
        float a0 = __expf(dt * A0); h0 = a0 * h0 + dt * Bv.x * xc;
        float a1 = __expf(dt * A1); h1 = a1 * h1 + dt * Bv.y * xc;
        float a2 = __expf(dt * A2); h2 = a2 * h2 + dt * Bv.z * xc;
        float a3 = __expf(dt * A3); h3 = a3 * h3 + dt * Bv.w * xc;
        float pp = h0 * Cv.x + h1 * Cv.y + h2 * Cv.z + h3 * Cv.w;
        pp += __shfl_xor(pp, 1);
        pp += __shfl_xor(pp, 2);
        if (sg == 0) p[d] = pp + Dd * xc;
    }
    __syncthreads();
    // gate: gy = y * silu(v . Wz), written back to SC's xc slot in global
    float* yb = sc + ((size_t)n * TLEN + t0) * 96;
    for (int i = threadIdx.x; i < nt * 32; i += 128) {
        int j = i >> 5, cc = i & 31;
        float z = 0.f;
#pragma unroll
        for (int k = 0; k < 16; k++) z += s_val[j][k] * s_wz[k][cc];
        yb[j * 96 + cc] = s_sc[j * 96 + cc] * siluf(z);
    }
}

// ---- unified phase 3 (fits3): block=(b,cube,co), thread=(i,j) out pixel ----
__global__ __launch_bounds__(256) void k_p3f(
    const float* __restrict__ SC0,
    const float* __restrict__ w0, const float* __restrict__ w12,
    float* __restrict__ out, size_t arena)
{
    int bid = blockIdx.x;
    int co = bid & 63, cube = (bid >> 6) & 63, b = bid >> 12;
    int tid = threadIdx.x, i = tid >> 4, j = tid & 15;
    int n = (b << 6) | cube;

    __shared__ float s_w0[512], s_w12[512];
    __shared__ __align__(16) float s_gy1[16][36], s_gy2[16][36];
    const float* sc1 = SC0 + arena;
    const float* sc2 = SC0 + 2 * arena;
    for (int q = tid; q < 512; q += 256) { s_w0[q] = w0[q]; s_w12[q] = w12[q]; }
    {
        size_t rbase = ((size_t)n * TLEN + co * 16 + 1) * 96;
        for (int q = tid; q < 16 * 8; q += 256) {
            int r = q >> 3, f4 = q & 7;
            *(float4*)&s_gy1[r][f4 * 4] = *(const float4*)&sc1[rbase + r * 96 + f4 * 4];
            *(float4*)&s_gy2[r][f4 * 4] = *(const float4*)&sc2[rbase + r * 96 + f4 * 4];
        }
    }
    __syncthreads();

    int coff = co & 3, oj = co >> 2;
    int l0 = (2 * i + (coff >> 1)) * 32 + 2 * j + (coff & 1);
    const float* y0 = SC0 + ((size_t)n * TLEN + l0 + 1) * 96;
    float o;
    {
        float acc = 0.f;
#pragma unroll
        for (int cc = 0; cc < 32; cc++) acc += y0[cc] * s_w0[oj * 32 + cc];
        o = acc * (1.0f / 3.0f);
    }
    {
        float acc = 0.f;
#pragma unroll
        for (int cc = 0; cc < 32; cc++) acc += s_gy1[j][cc] * s_w12[i * 32 + cc];
        o += acc * (1.0f / 3.0f);
    }
    {
        float acc = 0.f;
#pragma unroll
        for (int cc = 0; cc < 32; cc++) acc += s_gy2[i][cc] * s_w12[j * 32 + cc];
        o += acc * (1.0f / 3.0f);
    }
    int h = cube * 2 + (i >> 3), w = ((i & 7) << 4) | j;
    out[xidx(b, co, h, w)] = o;
}

// ---- per-mode phase 3 (fallback paths): gated y in SC, out-proj + scatter --
template <int MODE>
__global__ void k_p3m(const float* __restrict__ ysc,
                      const float* __restrict__ out_w,
                      float* __restrict__ out)
{
    __shared__ float s_w[16 * 32];
    for (int i = threadIdx.x; i < 512; i += blockDim.x) s_w[i] = out_w[i];
    __syncthreads();
    int tid = blockIdx.x * blockDim.x + threadIdx.x;
    if (tid >= NSEQ * LSEQ) return;
    int n = tid >> 10, l = tid & 1023, t = l + 1;
    const float* y = ysc + ((size_t)n * TLEN + t) * 96;
    float yv[32];
#pragma unroll
    for (int c = 0; c < 32; c++) yv[c] = y[c];
    float o[16];
#pragma unroll
    for (int j = 0; j < 16; j++) {
        float acc = 0.f;
#pragma unroll
        for (int c = 0; c < 32; c++) acc += yv[c] * s_w[j * 32 + c];
        o[j] = acc * (1.0f / 3.0f);
    }
    int b = n >> 6, cube = n & 63;
    if (MODE == 0) {
        int i2 = l >> 5, j2 = l & 31;
        int io = i2 >> 1, jo = j2 >> 1;
        int coff = ((i2 & 1) << 1) | (j2 & 1);
#pragma unroll
        for (int j = 0; j < 16; j++) out[oidx(b, cube, j * 4 + coff, io, jo)] = o[j];
    } else if (MODE == 1) {
        int c = l >> 4, jj = l & 15;
#pragma unroll
        for (int j = 0; j < 16; j++) out[oidx(b, cube, c, j, jj)] += o[j];
    } else {
        int c = l >> 4, ii = l & 15;
#pragma unroll
        for (int j = 0; j < 16; j++) out[oidx(b, cube, c, ii, j)] += o[j];
    }
}

}  // namespace

extern "C" void kernel_launch(void* const* d_in, const int* in_sizes, int n_in,
                              void* d_out, int out_size, void* d_ws, size_t ws_size,
                              hipStream_t stream) {
    const float* x   = (const float*)d_in[0];
    const float* gt1 = (const float*)d_in[1];
    const float* gt2 = (const float*)d_in[2];
    const float* ln1g = (const float*)d_in[3];
    const float* ln1b = (const float*)d_in[4];
    const float* ln2g = (const float*)d_in[5];
    const float* ln2b = (const float*)d_in[6];
    MP P[2];
    for (int mi = 0; mi < 2; mi++) {
        P[mi].in_w   = (const float*)d_in[7 + mi * 9 + 0];
        P[mi].conv_w = (const float*)d_in[7 + mi * 9 + 1];
        P[mi].conv_b = (const float*)d_in[7 + mi * 9 + 2];
        P[mi].xproj_w= (const float*)d_in[7 + mi * 9 + 3];
        P[mi].dt_w   = (const float*)d_in[7 + mi * 9 + 4];
        P[mi].dt_b   = (const float*)d_in[7 + mi * 9 + 5];
        P[mi].A_log  = (const float*)d_in[7 + mi * 9 + 6];
        P[mi].D      = (const float*)d_in[7 + mi * 9 + 7];
        P[mi].out_w  = (const float*)d_in[7 + mi * 9 + 8];
    }
    float* out = (float*)d_out;

    const size_t VBs = (size_t)NSEQ * TLEN * 16;
    const size_t SCs = (size_t)NSEQ * TLEN * 96;
    const size_t PS16 = (size_t)NSEQ * 16 * 512;
    const size_t PS32 = (size_t)NSEQ * 32 * 512;
    const size_t arena16 = VBs + SCs + 3 * PS16;
    const size_t arena32 = VBs + SCs + 3 * PS32;

    float* A0 = (float*)d_ws;
    dim3 b256(256), b128(128), b512(512);
    dim3 grd3((NSEQ * LSEQ + 255) / 256);

    const bool fits3_32 = ws_size >= 3 * arena32 * sizeof(float);
    const bool fits3_16 = ws_size >= 3 * arena16 * sizeof(float);
    const bool fits2_16 = ws_size >= 2 * arena16 * sizeof(float);

    if (fits3_32) {
        const size_t arena = arena32;
        auto VB = [&](int y) { return A0 + (size_t)y * arena; };
        auto SC = [&](int y) { return A0 + (size_t)y * arena + VBs; };
        auto PS = [&](int y) { return A0 + (size_t)y * arena + VBs + SCs; };
        auto FS = [&](int y) { return PS(y) + PS32; };
        auto HI = [&](int y) { return FS(y) + PS32; };
        k_p1<-1><<<dim3(NSEQ * NT, 3), b256, 0, stream>>>(
            x, gt1, gt2, ln1g, ln1b, ln2g, ln2b, P[0], P[1], 0, VB(0), SC(0), arena);
        k_scan1<-1, 33, 32><<<dim3(NSEQ * 32, 3), b128, 0, stream>>>(
            SC(0), P[0], P[1], 0, PS(0), FS(0), arena);
        k_comb<32><<<dim3(NSEQ, 3), b512, 0, stream>>>(PS(0), FS(0), HI(0), arena);
        k_scan2<-1, 33, 32><<<dim3(NSEQ * 32, 3), b128, 0, stream>>>(
            SC(0), VB(0), P[0], P[1], 0, HI(0), arena);
        k_p3f<<<dim3(NSEQ * 64), b256, 0, stream>>>(SC(0), P[0].out_w, P[1].out_w, out, arena);
    } else if (fits3_16) {
        const size_t arena = arena16;
        auto VB = [&](int y) { return A0 + (size_t)y * arena; };
        auto SC = [&](int y) { return A0 + (size_t)y * arena + VBs; };
        auto PS = [&](int y) { return A0 + (size_t)y * arena + VBs + SCs; };
        auto FS = [&](int y) { return PS(y) + PS16; };
        auto HI = [&](int y) { return FS(y) + PS16; };
        k_p1<-1><<<dim3(NSEQ * NT, 3), b256, 0, stream>>>(
            x, gt1, gt2, ln1g, ln1b, ln2g, ln2b, P[0], P[1], 0, VB(0), SC(0), arena);
        k_scan1<-1, 65, 16><<<dim3(NSEQ * 16, 3), b128, 0, stream>>>(
            SC(0), P[0], P[1], 0, PS(0), FS(0), arena);
        k_comb<16><<<dim3(NSEQ, 3), b512, 0, stream>>>(PS(0), FS(0), HI(0), arena);
        k_scan2<-1, 65, 16><<<dim3(NSEQ * 16, 3), b128, 0, stream>>>(
            SC(0), VB(0), P[0], P[1], 0, HI(0), arena);
        k_p3f<<<dim3(NSEQ * 64), b256, 0, stream>>>(SC(0), P[0].out_w, P[1].out_w, out, arena);
    } else if (fits2_16) {
        const size_t arena = arena16;
        auto VB = [&](int y) { return A0 + (size_t)y * arena; };
        auto SC = [&](int y) { return A0 + (size_t)y * arena + VBs; };
        auto PS = [&](int y) { return A0 + (size_t)y * arena + VBs + SCs; };
        auto FS = [&](int y) { return PS(y) + PS16; };
        auto HI = [&](int y) { return FS(y) + PS16; };
        k_p1<0><<<dim3(NSEQ * NT, 1), b256, 0, stream>>>(
            x, gt1, gt2, ln1g, ln1b, ln2g, ln2b, P[0], P[1], 0, VB(0), SC(0), arena);
        k_scan1<0, 65, 16><<<dim3(NSEQ * 16, 1), b128, 0, stream>>>(
            SC(0), P[0], P[1], 0, PS(0), FS(0), arena);
        k_comb<16><<<dim3(NSEQ, 1), b512, 0, stream>>>(PS(0), FS(0), HI(0), arena);
        k_scan2<0, 65, 16><<<dim3(NSEQ * 16, 1), b128, 0, stream>>>(
            SC(0), VB(0), P[0], P[1], 0, HI(0), arena);
        k_p3m<0><<<grd3, b256, 0, stream>>>(SC(0), P[0].out_w, out);
        k_p1<-1><<<dim3(NSEQ * NT, 2), b256, 0, stream>>>(
            x, gt1, gt2, ln1g, ln1b, ln2g, ln2b, P[0], P[1], 1, VB(0), SC(0), arena);
        k_scan1<-1, 65, 16><<<dim3(NSEQ * 16, 2), b128, 0, stream>>>(
            SC(0), P[0], P[1], 1, PS(0), FS(0), arena);
        k_comb<16><<<dim3(NSEQ, 2), b512, 0, stream>>>(PS(0), FS(0), HI(0), arena);
        k_scan2<-1, 65, 16><<<dim3(NSEQ * 16, 2), b128, 0, stream>>>(
            SC(0), VB(0), P[0], P[1], 1, HI(0), arena);
        k_p3m<1><<<grd3, b256, 0, stream>>>(SC(0), P[1].out_w, out);
        k_p3m<2><<<grd3, b256, 0, stream>>>(SC(1), P[1].out_w, out);
    } else {
        const size_t arena = arena16;
        auto VB = [&](int y) { return A0 + (size_t)y * arena; };
        auto SC = [&](int y) { return A0 + (size_t)y * arena + VBs; };
        auto PS = [&](int y) { return A0 + (size_t)y * arena + VBs + SCs; };
        auto FS = [&](int y) { return PS(y) + PS16; };
        auto HI = [&](int y) { return FS(y) + PS16; };
        for (int mode = 0; mode < 3; mode++) {
            if (mode == 0)
                k_p1<0><<<dim3(NSEQ * NT, 1), b256, 0, stream>>>(
                    x, gt1, gt2, ln1g, ln1b, ln2g, ln2b, P[0], P[1], 0, VB(0), SC(0), arena);
            else if (mode == 1)
                k_p1<1><<<dim3(NSEQ * NT, 1), b256, 0, stream>>>(
                    x, gt1, gt2, ln1g, ln1b, ln2g, ln2b, P[0], P[1], 0, VB(0), SC(0), arena);
            else
                k_p1<2><<<dim3(NSEQ * NT, 1), b256, 0, stream>>>(
                    x, gt1, gt2, ln1g, ln1b, ln2g, ln2b, P[0], P[1], 0, VB(0), SC(0), arena);
            if (mode == 0)
                k_scan1<0, 65, 16><<<dim3(NSEQ * 16, 1), b128, 0, stream>>>(SC(0), P[0], P[1], 0, PS(0), FS(0), arena);
            else if (mode == 1)
                k_scan1<1, 65, 16><<<dim3(NSEQ * 16, 1), b128, 0, stream>>>(SC(0), P[0], P[1], 0, PS(0), FS(0), arena);
            else
                k_scan1<2, 65, 16><<<dim3(NSEQ * 16, 1), b128, 0, stream>>>(SC(0), P[0], P[1], 0, PS(0), FS(0), arena);
            k_comb<16><<<dim3(NSEQ, 1), b512, 0, stream>>>(PS(0), FS(0), HI(0), arena);
            if (mode == 0)
                k_scan2<0, 65, 16><<<dim3(NSEQ * 16, 1), b128, 0, stream>>>(SC(0), VB(0), P[0], P[1], 0, HI(0), arena);
            else if (mode == 1)
                k_scan2<1, 65, 16><<<dim3(NSEQ * 16, 1), b128, 0, stream>>>(SC(0), VB(0), P[0], P[1], 0, HI(0), arena);
            else
                k_scan2<2, 65, 16><<<dim3(NSEQ * 16, 1), b128, 0, stream>>>(SC(0), VB(0), P[0], P[1], 0, HI(0), arena);
            if (mode == 0)      k_p3m<0><<<grd3, b256, 0, stream>>>(SC(0), P[0].out_w, out);
            else if (mode == 1) k_p3m<1><<<grd3, b256, 0, stream>>>(SC(0), P[1].out_w, out);
            else                k_p3m<2><<<grd3, b256, 0, stream>>>(SC(0), P[1].out_w, out);
        }
    }
}

// Round 22
// 291.215 us; speedup vs baseline: 1.1271x; 1.1271x over previous
//
#include <hip/hip_runtime.h>
#include <cmath>

namespace {

constexpr int XC = 64, XH = 128, XW = 128;
constexpr int NSEQ = 128;   // B(2) * 64 cubes
constexpr int TLEN = 1025;  // gt token + 1024
constexpr int LSEQ = 1024;
constexpr int TT = 96;      // token tile for fused p1
constexpr int NT = 11;      // ceil(1025/96)

struct MP {
    const float *in_w, *conv_w, *conv_b, *xproj_w, *dt_w, *dt_b, *A_log, *D, *out_w;
};

__device__ __forceinline__ int xidx(int b, int c, int h, int w) {
    return ((b * XC + c) * XH + h) * XW + w;
}
__device__ __forceinline__ int oidx(int b, int cube, int c, int i, int j) {
    int h = cube * 2 + (i >> 3);
    int w = ((i & 7) << 4) | j;
    return xidx(b, c, h, w);
}
__device__ __forceinline__ float siluf(float v) { return v / (1.0f + __expf(-v)); }
__device__ __forceinline__ float softplusf(float v) {
    return v > 20.0f ? v : log1pf(__expf(v));
}

template <int MODE>
__device__ __forceinline__ float gather_val(const float* __restrict__ x,
                                            const float* __restrict__ s_gt,
                                            int t, int k, int b, int bi, int bj) {
    if (t == 0) return s_gt[k];
    int l = t - 1;
    if (MODE == 0) {
        int i2 = l >> 5, j2 = l & 31;
        int h = bi * 16 + (i2 >> 1), w = bj * 16 + (j2 >> 1);
        int coff = ((i2 & 1) << 1) | (j2 & 1);
        return x[xidx(b, k * 4 + coff, h, w)];
    } else if (MODE == 1) {
        int c = l >> 4, j = l & 15;
        return x[xidx(b, c, bi * 16 + k, bj * 16 + j)];
    } else {
        int c = l >> 4, i = l & 15;
        return x[xidx(b, c, bi * 16 + i, bj * 16 + k)];
    }
}
__device__ __forceinline__ float gather_rt(int mode, const float* __restrict__ x,
                                           const float* __restrict__ s_gt,
                                           int t, int k, int b, int bi, int bj) {
    if (mode == 0) return gather_val<0>(x, s_gt, t, k, b, bi, bj);
    if (mode == 1) return gather_val<1>(x, s_gt, t, k, b, bi, bj);
    return gather_val<2>(x, s_gt, t, k, b, bi, bj);
}

// ==== phase 1: gather+LN+in-proj(xi)+conv+x-proj; LN output v -> VB =========
template <int MODE_C>
__global__ __launch_bounds__(256) void k_p1(
    const float* __restrict__ x,
    const float* __restrict__ gt1, const float* __restrict__ gt2,
    const float* __restrict__ ln1g, const float* __restrict__ ln1b,
    const float* __restrict__ ln2g, const float* __restrict__ ln2b,
    MP P0, MP P1, int mode_base,
    float* __restrict__ VB0, float* __restrict__ SC0, size_t arena)
{
    const int mode = (MODE_C >= 0) ? MODE_C : (mode_base + (int)blockIdx.y);
    const MP P = (mode == 0) ? P0 : P1;
    const float* gt  = (mode == 0) ? gt1 : gt2;
    const float* lng = (mode == 0) ? ln1g : ln2g;
    const float* lnb = (mode == 0) ? ln1b : ln2b;
    float* VB = VB0 + (size_t)blockIdx.y * arena;
    float* sc = SC0 + (size_t)blockIdx.y * arena;

    const int n = blockIdx.x / NT, tile = blockIdx.x % NT;
    const int t0 = tile * TT;
    const int ntk = min(TT, TLEN - t0);
    const int nth = ntk + 3;  // with 3-token front halo
    const int b = n >> 6, cube = n & 63, bi = cube >> 3, bj = cube & 7;
    const int tid = threadIdx.x;

    __shared__ __align__(16) float s_pool[TT * 37];
    float (*s_v)[17]  = (float(*)[17])s_pool;
    float (*s_xc)[37] = (float(*)[37])s_pool;
    __shared__ __align__(16) float s_xi[TT + 3][36];
    __shared__ __align__(16) float s_wT[16][32];   // in_w rows 0..31 transposed
    __shared__ __align__(16) float s_xpT[32][36];  // s_xpT[cc][q] = xproj_w[q+1][cc]
    __shared__ float s_xp0[32];
    __shared__ float s_cw[128], s_cb[32], s_dw[32], s_db[32];
    __shared__ float s_g[16], s_bb[16], s_gt[16];
    __shared__ float s_dt0[TT];

    for (int i = tid; i < 32 * 16; i += 256) s_wT[i & 15][i >> 4] = P.in_w[i];
    for (int i = tid; i < 33 * 32; i += 256) {
        int r = i >> 5, cc = i & 31;
        float v = P.xproj_w[i];
        if (r == 0) s_xp0[cc] = v;
        else s_xpT[cc][r - 1] = v;
    }
    if (tid < 128) s_cw[tid] = P.conv_w[tid];
    if (tid < 32) { s_cb[tid] = P.conv_b[tid]; s_dw[tid] = P.dt_w[tid]; s_db[tid] = P.dt_b[tid]; }
    if (tid < 16) { s_g[tid] = lng[tid]; s_bb[tid] = lnb[tid]; s_gt[tid] = gt[tid]; }
    __syncthreads();

    // ---- gather, element-per-thread
    for (int it = tid; it < nth * 16; it += 256) {
        int tl = it >> 4, k = it & 15;
        int t = t0 - 3 + tl;
        float v;
        if (t < 0) v = 0.f;
        else if (MODE_C >= 0) v = gather_val<(MODE_C >= 0 ? MODE_C : 0)>(x, s_gt, t, k, b, bi, bj);
        else v = gather_rt(mode, x, s_gt, t, k, b, bi, bj);
        s_v[tl][k] = v;
    }
    __syncthreads();

    // ---- layernorm, token-per-thread from LDS
    for (int tl = tid; tl < nth; tl += 256) {
        int t = t0 - 3 + tl;
        if (t < 0) continue;
        float v[16], mu = 0.f;
#pragma unroll
        for (int k = 0; k < 16; k++) { v[k] = s_v[tl][k]; mu += v[k]; }
        mu *= (1.f / 16.f);
        float var = 0.f;
#pragma unroll
        for (int k = 0; k < 16; k++) { float d = v[k] - mu; var += d * d; }
        float inv = rsqrtf(var * (1.f / 16.f) + 1e-5f);
#pragma unroll
        for (int k = 0; k < 16; k++) s_v[tl][k] = (v[k] - mu) * inv * s_g[k] + s_bb[k];
    }
    __syncthreads();

    // ---- VB store (LN output) + in-proj xi half, 4tok x 4oc tiles
    {
        float* vb = VB + ((size_t)n * TLEN + t0) * 16;
        for (int it = tid; it < ntk * 16; it += 256) {
            int j = it >> 4, k = it & 15;
            vb[it] = s_v[j + 3][k];
        }
        const int ntt = (nth + 3) >> 2;
        for (int tl0 = tid; tl0 < ntt * 8; tl0 += 256) {
            int tt = tl0 >> 3, og = tl0 & 7;
            int oc = og * 4;
            float acc[4][4] = {{0.f}};
#pragma unroll
            for (int k = 0; k < 16; k++) {
                float4 wv = *(const float4*)&s_wT[k][oc];
                float a0 = s_v[4 * tt + 0][k];
                float a1 = s_v[4 * tt + 1][k];
                float a2 = s_v[4 * tt + 2][k];
                float a3 = s_v[4 * tt + 3][k];
                acc[0][0] += a0 * wv.x; acc[0][1] += a0 * wv.y; acc[0][2] += a0 * wv.z; acc[0][3] += a0 * wv.w;
                acc[1][0] += a1 * wv.x; acc[1][1] += a1 * wv.y; acc[1][2] += a1 * wv.z; acc[1][3] += a1 * wv.w;
                acc[2][0] += a2 * wv.x; acc[2][1] += a2 * wv.y; acc[2][2] += a2 * wv.z; acc[2][3] += a2 * wv.w;
                acc[3][0] += a3 * wv.x; acc[3][1] += a3 * wv.y; acc[3][2] += a3 * wv.z; acc[3][3] += a3 * wv.w;
            }
#pragma unroll
            for (int i = 0; i < 4; i++) {
                int tl = 4 * tt + i;
                if (tl >= nth) break;
                *(float4*)&s_xi[tl][oc] =
                    make_float4(acc[i][0], acc[i][1], acc[i][2], acc[i][3]);
            }
        }
    }
    __syncthreads();  // s_v dead; pool becomes s_xc

    // ---- conv4 + silu; emit xc to global inline
    {
        int cc = tid & 31, jg = tid >> 5;
        float c0 = s_cw[cc * 4 + 0], c1 = s_cw[cc * 4 + 1];
        float c2 = s_cw[cc * 4 + 2], c3 = s_cw[cc * 4 + 3];
        float cb = s_cb[cc];
        float* scb = sc + ((size_t)n * TLEN + t0) * 96;
        for (int j = jg; j < ntk; j += 8) {
            float acc = 0.f;
            acc += c0 * s_xi[j + 0][cc];
            acc += c1 * s_xi[j + 1][cc];
            acc += c2 * s_xi[j + 2][cc];
            acc += c3 * s_xi[j + 3][cc];
            float v = siluf(acc + cb);
            s_xc[j][cc] = v;
            scb[j * 96 + cc] = v;
        }
    }
    __syncthreads();

    // ---- x-proj B/C rows, 4-token x 4-q register tile
    {
        int qt = tid & 7, tt = tid >> 3;
        if (4 * tt < ntk) {
            float acc[4][4] = {{0.f}};
#pragma unroll
            for (int cc = 0; cc < 32; cc++) {
                float4 wv = *(const float4*)&s_xpT[cc][4 * qt];
                float a0 = s_xc[4 * tt + 0][cc];
                float a1 = s_xc[4 * tt + 1][cc];
                float a2 = s_xc[4 * tt + 2][cc];
                float a3 = s_xc[4 * tt + 3][cc];
                acc[0][0] += a0 * wv.x; acc[0][1] += a0 * wv.y; acc[0][2] += a0 * wv.z; acc[0][3] += a0 * wv.w;
                acc[1][0] += a1 * wv.x; acc[1][1] += a1 * wv.y; acc[1][2] += a1 * wv.z; acc[1][3] += a1 * wv.w;
                acc[2][0] += a2 * wv.x; acc[2][1] += a2 * wv.y; acc[2][2] += a2 * wv.z; acc[2][3] += a2 * wv.w;
                acc[3][0] += a3 * wv.x; acc[3][1] += a3 * wv.y; acc[3][2] += a3 * wv.z; acc[3][3] += a3 * wv.w;
            }
#pragma unroll
            for (int i = 0; i < 4; i++) {
                int j = 4 * tt + i;
                if (j < ntk)
                    *(float4*)&sc[((size_t)n * TLEN + t0 + j) * 96 + 64 + 4 * qt] =
                        make_float4(acc[i][0], acc[i][1], acc[i][2], acc[i][3]);
            }
        }
        if (tid < ntk) {
            float acc = 0.f;
#pragma unroll
            for (int cc = 0; cc < 32; cc++) acc += s_xc[tid][cc] * s_xp0[cc];
            s_dt0[tid] = acc;
        }
    }
    __syncthreads();

    // ---- dt block emit
    {
        float* scb = sc + ((size_t)n * TLEN + t0) * 96;
        for (int it = tid; it < ntk * 32; it += 256) {
            int j = it >> 5, d = it & 31;
            scb[j * 96 + 32 + d] = softplusf(s_dt0[j] * s_dw[d] + s_db[d]);
        }
    }
}

// -------- phase 2a: per-chunk scan summaries; stage only xc/dt/B (80 f) -----
template <int MODE_C, int CHUNKT, int NCHT>
__global__ __launch_bounds__(128) void k_scan1(
    const float* __restrict__ SC0, MP P0, MP P1, int mode_base,
    float* __restrict__ PS0, float* __restrict__ FS0, size_t arena)
{
    const int mode = (MODE_C >= 0) ? MODE_C : (mode_base + (int)blockIdx.y);
    const float* A_log = (mode == 0) ? P0.A_log : P1.A_log;
    const float* sc = SC0 + (size_t)blockIdx.y * arena;
    float* Psum = PS0 + (size_t)blockIdx.y * arena;
    float* Fsum = FS0 + (size_t)blockIdx.y * arena;

    int n = blockIdx.x / NCHT;
    int c = blockIdx.x % NCHT;
    int t0 = c * CHUNKT;
    int nt = min(CHUNKT, TLEN - t0);
    __shared__ __align__(16) float s_sc[CHUNKT * 80];   // xc[32] dt[32] B[16]
    const float* src = sc + ((size_t)n * TLEN + t0) * 96;
    for (int i = threadIdx.x; i < nt * 20; i += 128) {
        int row = i / 20, q = i - row * 20;
        ((float4*)s_sc)[row * 20 + q] = *(const float4*)&src[row * 96 + q * 4];
    }
    int tid = threadIdx.x, d = tid >> 2, sg = tid & 3;
    float4 Av = *(const float4*)&A_log[d * 16 + sg * 4];
    float A0 = -__expf(Av.x), A1 = -__expf(Av.y), A2 = -__expf(Av.z), A3 = -__expf(Av.w);
    __syncthreads();
    float h0 = 0.f, h1 = 0.f, h2 = 0.f, h3 = 0.f;
    float P0v = 1.f, P1v = 1.f, P2v = 1.f, P3v = 1.f;
    for (int t = 0; t < nt; t++) {
        const float* p = s_sc + t * 80;
        float dt = p[32 + d], xc = p[d];
        float4 Bv = *(const float4*)&p[64 + sg * 4];
        float a0 = __expf(dt * A0); h0 = a0 * h0 + dt * Bv.x * xc; P0v *= a0;
        float a1 = __expf(dt * A1); h1 = a1 * h1 + dt * Bv.y * xc; P1v *= a1;
        float a2 = __expf(dt * A2); h2 = a2 * h2 + dt * Bv.z * xc; P2v *= a2;
        float a3 = __expf(dt * A3); h3 = a3 * h3 + dt * Bv.w * xc; P3v *= a3;
    }
    size_t base = ((size_t)n * NCHT + c) * 512 + d * 16 + sg * 4;
    *(float4*)&Psum[base] = make_float4(P0v, P1v, P2v, P3v);
    *(float4*)&Fsum[base] = make_float4(h0, h1, h2, h3);
}

// -------- phase 2b: combine chunk summaries -> incoming state per chunk -----
template <int NCHT>
__global__ __launch_bounds__(512) void k_comb(
    const float* __restrict__ PS0, const float* __restrict__ FS0,
    float* __restrict__ HI0, size_t arena)
{
    const float* Psum = PS0 + (size_t)blockIdx.y * arena;
    const float* Fsum = FS0 + (size_t)blockIdx.y * arena;
    float* Hin = HI0 + (size_t)blockIdx.y * arena;
    int n = blockIdx.x, tid = threadIdx.x;
    const float* pb = Psum + (size_t)n * NCHT * 512;
    const float* fb = Fsum + (size_t)n * NCHT * 512;
    float* hb = Hin + (size_t)n * NCHT * 512;
    float H = 0.f;
#pragma unroll
    for (int c = 0; c < NCHT; c++) {
        float P = pb[(size_t)c * 512 + tid];
        float F = fb[(size_t)c * 512 + tid];
        hb[(size_t)c * 512 + tid] = H;
        H = F + P * H;
    }
}

// --- phase 2c: scan pass 2; y overwrites staged xc slot in LDS, then SC -----
template <int MODE_C, int CHUNKT, int NCHT>
__global__ __launch_bounds__(128) void k_scan2(
    float* __restrict__ SC0, MP P0, MP P1, int mode_base,
    const float* __restrict__ HI0, size_t arena)
{
    const int mode = (MODE_C >= 0) ? MODE_C : (mode_base + (int)blockIdx.y);
    const float* A_log = (mode == 0) ? P0.A_log : P1.A_log;
    const float* Dp = (mode == 0) ? P0.D : P1.D;
    float* sc = SC0 + (size_t)blockIdx.y * arena;
    const float* Hin = HI0 + (size_t)blockIdx.y * arena;

    int n = blockIdx.x / NCHT;
    int c = blockIdx.x % NCHT;
    int t0 = c * CHUNKT;
    int nt = min(CHUNKT, TLEN - t0);
    __shared__ __align__(16) float s_sc[CHUNKT * 96];
    const float* src = sc + ((size_t)n * TLEN + t0) * 96;
    int nv4 = nt * 24;
    for (int i = threadIdx.x; i < nv4; i += 128)
        ((float4*)s_sc)[i] = ((const float4*)src)[i];
    int tid = threadIdx.x, d = tid >> 2, sg = tid & 3;
    float4 Av = *(const float4*)&A_log[d * 16 + sg * 4];
    float A0 = -__expf(Av.x), A1 = -__expf(Av.y), A2 = -__expf(Av.z), A3 = -__expf(Av.w);
    float Dd = Dp[d];
    float4 Hv = *(const float4*)&Hin[((size_t)n * NCHT + c) * 512 + d * 16 + sg * 4];
    float h0 = Hv.x, h1 = Hv.y, h2 = Hv.z, h3 = Hv.w;
    __syncthreads();
    for (int t = 0; t < nt; t++) {
        float* p = s_sc + t * 96;
        float dt = p[32 + d], xc = p[d];
        float4 Bv = *(const float4*)&p[64 + sg * 4];
        float4 Cv = *(const float4*)&p[80 + sg * 4];
        float a0 = __expf(dt * A0); h0 = a0 * h0 + dt * Bv.x * xc;
        float a1 = __expf(dt * A1); h1 = a1 * h1 + dt * Bv.y * xc;
        float a2 = __expf(dt * A2); h2 = a2 * h2 + dt * Bv.z * xc;
        float a3 = __expf(dt * A3); h3 = a3 * h3 + dt * Bv.w * xc;
        float pp = h0 * Cv.x + h1 * Cv.y + h2 * Cv.z + h3 * Cv.w;
        pp += __shfl_xor(pp, 1);
        pp += __shfl_xor(pp, 2);
        if (sg == 0) p[d] = pp + Dd * xc;
    }
    __syncthreads();
    float* yb = sc + ((size_t)n * TLEN + t0) * 96;
    for (int i = threadIdx.x; i < nt * 8; i += 128) {
        int j = i >> 3, q = i & 7;
        *(float4*)&yb[j * 96 + q * 4] = *(const float4*)&s_sc[j * 96 + q * 4];
    }
}

// -------- phase 3: z from VB + gate + out-proj + scatter (per-mode) ---------
template <int MODE>
__global__ void k_p3(const float* __restrict__ ysc, const float* __restrict__ VB,
                     const float* __restrict__ in_w,   // (64,16), rows 32..63 = z
                     const float* __restrict__ out_w,  // (16,32)
                     float* __restrict__ out)
{
    __shared__ float s_w[16 * 32];
    __shared__ float s_wz[16][32];
    for (int i = threadIdx.x; i < 512; i += blockDim.x) {
        s_w[i] = out_w[i];
        int oc = i >> 4, k = i & 15;
        s_wz[k][oc] = in_w[(32 + oc) * 16 + k];
    }
    __syncthreads();
    int tid = blockIdx.x * blockDim.x + threadIdx.x;
    if (tid >= NSEQ * LSEQ) return;
    int n = tid >> 10, l = tid & 1023, t = l + 1;
    const float* y = ysc + ((size_t)n * TLEN + t) * 96;
    const float* vv = VB + ((size_t)n * TLEN + t) * 16;
    float v[16];
#pragma unroll
    for (int k = 0; k < 16; k++) v[k] = vv[k];
    float yv[32];
#pragma unroll
    for (int c = 0; c < 32; c++) {
        float z = 0.f;
#pragma unroll
        for (int k = 0; k < 16; k++) z += v[k] * s_wz[k][c];
        yv[c] = y[c] * siluf(z);
    }
    float o[16];
#pragma unroll
    for (int j = 0; j < 16; j++) {
        float acc = 0.f;
#pragma unroll
        for (int c = 0; c < 32; c++) acc += yv[c] * s_w[j * 32 + c];
        o[j] = acc * (1.0f / 3.0f);
    }
    int b = n >> 6, cube = n & 63;
    if (MODE == 0) {
        int i2 = l >> 5, j2 = l & 31;
        int io = i2 >> 1, jo = j2 >> 1;
        int coff = ((i2 & 1) << 1) | (j2 & 1);
#pragma unroll
        for (int j = 0; j < 16; j++) out[oidx(b, cube, j * 4 + coff, io, jo)] = o[j];
    } else if (MODE == 1) {
        int c = l >> 4, jj = l & 15;
#pragma unroll
        for (int j = 0; j < 16; j++) out[oidx(b, cube, c, j, jj)] += o[j];
    } else {
        int c = l >> 4, ii = l & 15;
#pragma unroll
        for (int j = 0; j < 16; j++) out[oidx(b, cube, c, ii, j)] += o[j];
    }
}

}  // namespace

extern "C" void kernel_launch(void* const* d_in, const int* in_sizes, int n_in,
                              void* d_out, int out_size, void* d_ws, size_t ws_size,
                              hipStream_t stream) {
    const float* x   = (const float*)d_in[0];
    const float* gt1 = (const float*)d_in[1];
    const float* gt2 = (const float*)d_in[2];
    const float* ln1g = (const float*)d_in[3];
    const float* ln1b = (const float*)d_in[4];
    const float* ln2g = (const float*)d_in[5];
    const float* ln2b = (const float*)d_in[6];
    MP P[2];
    for (int mi = 0; mi < 2; mi++) {
        P[mi].in_w   = (const float*)d_in[7 + mi * 9 + 0];
        P[mi].conv_w = (const float*)d_in[7 + mi * 9 + 1];
        P[mi].conv_b = (const float*)d_in[7 + mi * 9 + 2];
        P[mi].xproj_w= (const float*)d_in[7 + mi * 9 + 3];
        P[mi].dt_w   = (const float*)d_in[7 + mi * 9 + 4];
        P[mi].dt_b   = (const float*)d_in[7 + mi * 9 + 5];
        P[mi].A_log  = (const float*)d_in[7 + mi * 9 + 6];
        P[mi].D      = (const float*)d_in[7 + mi * 9 + 7];
        P[mi].out_w  = (const float*)d_in[7 + mi * 9 + 8];
    }
    float* out = (float*)d_out;

    const size_t VBs = (size_t)NSEQ * TLEN * 16;
    const size_t SCs = (size_t)NSEQ * TLEN * 96;
    const size_t PS16 = (size_t)NSEQ * 16 * 512;
    const size_t PS32 = (size_t)NSEQ * 32 * 512;
    const size_t arena16 = VBs + SCs + 3 * PS16;   // 71.4 MB
    const size_t arena32 = VBs + SCs + 3 * PS32;   // 84.0 MB

    float* A0 = (float*)d_ws;
    dim3 b256(256), b128(128), b512(512);
    dim3 grd3((NSEQ * LSEQ + 255) / 256);

    const bool fits3_32 = ws_size >= 3 * arena32 * sizeof(float);
    const bool fits3_16 = ws_size >= 3 * arena16 * sizeof(float);
    const bool fits2_16 = ws_size >= 2 * arena16 * sizeof(float);

    if (fits3_32) {
        const size_t arena = arena32;
        auto VB = [&](int y) { return A0 + (size_t)y * arena; };
        auto SC = [&](int y) { return A0 + (size_t)y * arena + VBs; };
        auto PS = [&](int y) { return A0 + (size_t)y * arena + VBs + SCs; };
        auto FS = [&](int y) { return PS(y) + PS32; };
        auto HI = [&](int y) { return FS(y) + PS32; };
        k_p1<-1><<<dim3(NSEQ * NT, 3), b256, 0, stream>>>(
            x, gt1, gt2, ln1g, ln1b, ln2g, ln2b, P[0], P[1], 0, VB(0), SC(0), arena);
        k_scan1<-1, 33, 32><<<dim3(NSEQ * 32, 3), b128, 0, stream>>>(
            SC(0), P[0], P[1], 0, PS(0), FS(0), arena);
        k_comb<32><<<dim3(NSEQ, 3), b512, 0, stream>>>(PS(0), FS(0), HI(0), arena);
        k_scan2<-1, 33, 32><<<dim3(NSEQ * 32, 3), b128, 0, stream>>>(
            SC(0), P[0], P[1], 0, HI(0), arena);
        k_p3<0><<<grd3, b256, 0, stream>>>(SC(0), VB(0), P[0].in_w, P[0].out_w, out);
        k_p3<1><<<grd3, b256, 0, stream>>>(SC(1), VB(1), P[1].in_w, P[1].out_w, out);
        k_p3<2><<<grd3, b256, 0, stream>>>(SC(2), VB(2), P[1].in_w, P[1].out_w, out);
    } else if (fits3_16) {
        const size_t arena = arena16;
        auto VB = [&](int y) { return A0 + (size_t)y * arena; };
        auto SC = [&](int y) { return A0 + (size_t)y * arena + VBs; };
        auto PS = [&](int y) { return A0 + (size_t)y * arena + VBs + SCs; };
        auto FS = [&](int y) { return PS(y) + PS16; };
        auto HI = [&](int y) { return FS(y) + PS16; };
        k_p1<-1><<<dim3(NSEQ * NT, 3), b256, 0, stream>>>(
            x, gt1, gt2, ln1g, ln1b, ln2g, ln2b, P[0], P[1], 0, VB(0), SC(0), arena);
        k_scan1<-1, 65, 16><<<dim3(NSEQ * 16, 3), b128, 0, stream>>>(
            SC(0), P[0], P[1], 0, PS(0), FS(0), arena);
        k_comb<16><<<dim3(NSEQ, 3), b512, 0, stream>>>(PS(0), FS(0), HI(0), arena);
        k_scan2<-1, 65, 16><<<dim3(NSEQ * 16, 3), b128, 0, stream>>>(
            SC(0), P[0], P[1], 0, HI(0), arena);
        k_p3<0><<<grd3, b256, 0, stream>>>(SC(0), VB(0), P[0].in_w, P[0].out_w, out);
        k_p3<1><<<grd3, b256, 0, stream>>>(SC(1), VB(1), P[1].in_w, P[1].out_w, out);
        k_p3<2><<<grd3, b256, 0, stream>>>(SC(2), VB(2), P[1].in_w, P[1].out_w, out);
    } else if (fits2_16) {
        const size_t arena = arena16;
        auto VB = [&](int y) { return A0 + (size_t)y * arena; };
        auto SC = [&](int y) { return A0 + (size_t)y * arena + VBs; };
        auto PS = [&](int y) { return A0 + (size_t)y * arena + VBs + SCs; };
        auto FS = [&](int y) { return PS(y) + PS16; };
        auto HI = [&](int y) { return FS(y) + PS16; };
        k_p1<0><<<dim3(NSEQ * NT, 1), b256, 0, stream>>>(
            x, gt1, gt2, ln1g, ln1b, ln2g, ln2b, P[0], P[1], 0, VB(0), SC(0), arena);
        k_scan1<0, 65, 16><<<dim3(NSEQ * 16, 1), b128, 0, stream>>>(
            SC(0), P[0], P[1], 0, PS(0), FS(0), arena);
        k_comb<16><<<dim3(NSEQ, 1), b512, 0, stream>>>(PS(0), FS(0), HI(0), arena);
        k_scan2<0, 65, 16><<<dim3(NSEQ * 16, 1), b128, 0, stream>>>(
            SC(0), P[0], P[1], 0, HI(0), arena);
        k_p3<0><<<grd3, b256, 0, stream>>>(SC(0), VB(0), P[0].in_w, P[0].out_w, out);
        k_p1<-1><<<dim3(NSEQ * NT, 2), b256, 0, stream>>>(
            x, gt1, gt2, ln1g, ln1b, ln2g, ln2b, P[0], P[1], 1, VB(0), SC(0), arena);
        k_scan1<-1, 65, 16><<<dim3(NSEQ * 16, 2), b128, 0, stream>>>(
            SC(0), P[0], P[1], 1, PS(0), FS(0), arena);
        k_comb<16><<<dim3(NSEQ, 2), b512, 0, stream>>>(PS(0), FS(0), HI(0), arena);
        k_scan2<-1, 65, 16><<<dim3(NSEQ * 16, 2), b128, 0, stream>>>(
            SC(0), P[0], P[1], 1, HI(0), arena);
        k_p3<1><<<grd3, b256, 0, stream>>>(SC(0), VB(0), P[1].in_w, P[1].out_w, out);
        k_p3<2><<<grd3, b256, 0, stream>>>(SC(1), VB(1), P[1].in_w, P[1].out_w, out);
    } else {
        const size_t arena = arena16;
        auto VB = [&](int y) { return A0 + (size_t)y * arena; };
        auto SC = [&](int y) { return A0 + (size_t)y * arena + VBs; };
        auto PS = [&](int y) { return A0 + (size_t)y * arena + VBs + SCs; };
        auto FS = [&](int y) { return PS(y) + PS16; };
        auto HI = [&](int y) { return FS(y) + PS16; };
        for (int mode = 0; mode < 3; mode++) {
            if (mode == 0)
                k_p1<0><<<dim3(NSEQ * NT, 1), b256, 0, stream>>>(
                    x, gt1, gt2, ln1g, ln1b, ln2g, ln2b, P[0], P[1], 0, VB(0), SC(0), arena);
            else if (mode == 1)
                k_p1<1><<<dim3(NSEQ * NT, 1), b256, 0, stream>>>(
                    x, gt1, gt2, ln1g, ln1b, ln2g, ln2b, P[0], P[1], 0, VB(0), SC(0), arena);
            else
                k_p1<2><<<dim3(NSEQ * NT, 1), b256, 0, stream>>>(
                    x, gt1, gt2, ln1g, ln1b, ln2g, ln2b, P[0], P[1], 0, VB(0), SC(0), arena);
            if (mode == 0)
                k_scan1<0, 65, 16><<<dim3(NSEQ * 16, 1), b128, 0, stream>>>(SC(0), P[0], P[1], 0, PS(0), FS(0), arena);
            else if (mode == 1)
                k_scan1<1, 65, 16><<<dim3(NSEQ * 16, 1), b128, 0, stream>>>(SC(0), P[0], P[1], 0, PS(0), FS(0), arena);
            else
                k_scan1<2, 65, 16><<<dim3(NSEQ * 16, 1), b128, 0, stream>>>(SC(0), P[0], P[1], 0, PS(0), FS(0), arena);
            k_comb<16><<<dim3(NSEQ, 1), b512, 0, stream>>>(PS(0), FS(0), HI(0), arena);
            if (mode == 0)
                k_scan2<0, 65, 16><<<dim3(NSEQ * 16, 1), b128, 0, stream>>>(SC(0), P[0], P[1], 0, HI(0), arena);
            else if (mode == 1)
                k_scan2<1, 65, 16><<<dim3(NSEQ * 16, 1), b128, 0, stream>>>(SC(0), P[0], P[1], 0, HI(0), arena);
            else
                k_scan2<2, 65, 16><<<dim3(NSEQ * 16, 1), b128, 0, stream>>>(SC(0), P[0], P[1], 0, HI(0), arena);
            if (mode == 0)      k_p3<0><<<grd3, b256, 0, stream>>>(SC(0), VB(0), P[0].in_w, P[0].out_w, out);
            else if (mode == 1) k_p3<1><<<grd3, b256, 0, stream>>>(SC(0), VB(0), P[1].in_w, P[1].out_w, out);
            else                k_p3<2><<<grd3, b256, 0, stream>>>(SC(0), VB(0), P[1].in_w, P[1].out_w, out);
        }
    }
}

// Round 23
// 290.769 us; speedup vs baseline: 1.1288x; 1.0015x over previous
//
#include <hip/hip_runtime.h>
#include <cmath>

namespace {

constexpr int XC = 64, XH = 128, XW = 128;
constexpr int NSEQ = 128;   // B(2) * 64 cubes
constexpr int TLEN = 1025;  // gt token + 1024
constexpr int LSEQ = 1024;
constexpr int TT = 96;      // token tile for fused p1
constexpr int NT = 11;      // ceil(1025/96)

struct MP {
    const float *in_w, *conv_w, *conv_b, *xproj_w, *dt_w, *dt_b, *A_log, *D, *out_w;
};

__device__ __forceinline__ int xidx(int b, int c, int h, int w) {
    return ((b * XC + c) * XH + h) * XW + w;
}
__device__ __forceinline__ int oidx(int b, int cube, int c, int i, int j) {
    int h = cube * 2 + (i >> 3);
    int w = ((i & 7) << 4) | j;
    return xidx(b, c, h, w);
}
__device__ __forceinline__ float siluf(float v) { return v / (1.0f + __expf(-v)); }
__device__ __forceinline__ float softplusf(float v) {
    return v > 20.0f ? v : log1pf(__expf(v));
}

template <int MODE>
__device__ __forceinline__ float gather_val(const float* __restrict__ x,
                                            const float* __restrict__ s_gt,
                                            int t, int k, int b, int bi, int bj) {
    if (t == 0) return s_gt[k];
    int l = t - 1;
    if (MODE == 0) {
        int i2 = l >> 5, j2 = l & 31;
        int h = bi * 16 + (i2 >> 1), w = bj * 16 + (j2 >> 1);
        int coff = ((i2 & 1) << 1) | (j2 & 1);
        return x[xidx(b, k * 4 + coff, h, w)];
    } else if (MODE == 1) {
        int c = l >> 4, j = l & 15;
        return x[xidx(b, c, bi * 16 + k, bj * 16 + j)];
    } else {
        int c = l >> 4, i = l & 15;
        return x[xidx(b, c, bi * 16 + i, bj * 16 + k)];
    }
}
__device__ __forceinline__ float gather_rt(int mode, const float* __restrict__ x,
                                           const float* __restrict__ s_gt,
                                           int t, int k, int b, int bi, int bj) {
    if (mode == 0) return gather_val<0>(x, s_gt, t, k, b, bi, bj);
    if (mode == 1) return gather_val<1>(x, s_gt, t, k, b, bi, bj);
    return gather_val<2>(x, s_gt, t, k, b, bi, bj);
}

// ==== phase 1: gather+LN+in-proj(xi)+conv+x-proj; LN output v -> VB =========
template <int MODE_C>
__global__ __launch_bounds__(256, 5) void k_p1(
    const float* __restrict__ x,
    const float* __restrict__ gt1, const float* __restrict__ gt2,
    const float* __restrict__ ln1g, const float* __restrict__ ln1b,
    const float* __restrict__ ln2g, const float* __restrict__ ln2b,
    MP P0, MP P1, int mode_base,
    float* __restrict__ VB0, float* __restrict__ SC0, size_t arena)
{
    const int mode = (MODE_C >= 0) ? MODE_C : (mode_base + (int)blockIdx.y);
    const MP P = (mode == 0) ? P0 : P1;
    const float* gt  = (mode == 0) ? gt1 : gt2;
    const float* lng = (mode == 0) ? ln1g : ln2g;
    const float* lnb = (mode == 0) ? ln1b : ln2b;
    float* VB = VB0 + (size_t)blockIdx.y * arena;
    float* sc = SC0 + (size_t)blockIdx.y * arena;

    const int n = blockIdx.x / NT, tile = blockIdx.x % NT;
    const int t0 = tile * TT;
    const int ntk = min(TT, TLEN - t0);
    const int nth = ntk + 3;  // with 3-token front halo
    const int b = n >> 6, cube = n & 63, bi = cube >> 3, bj = cube & 7;
    const int tid = threadIdx.x;

    __shared__ __align__(16) float s_pool[TT * 37];
    float (*s_v)[17]  = (float(*)[17])s_pool;
    float (*s_xc)[37] = (float(*)[37])s_pool;
    __shared__ __align__(16) float s_xi[TT + 3][36];
    __shared__ __align__(16) float s_wT[16][32];   // in_w rows 0..31 transposed
    __shared__ __align__(16) float s_xpT[32][36];  // s_xpT[cc][q] = xproj_w[q+1][cc]
    __shared__ float s_xp0[32];
    __shared__ float s_cw[128], s_cb[32], s_dw[32], s_db[32];
    __shared__ float s_g[16], s_bb[16], s_gt[16];
    __shared__ float s_dt0[TT];

    for (int i = tid; i < 32 * 16; i += 256) s_wT[i & 15][i >> 4] = P.in_w[i];
    for (int i = tid; i < 33 * 32; i += 256) {
        int r = i >> 5, cc = i & 31;
        float v = P.xproj_w[i];
        if (r == 0) s_xp0[cc] = v;
        else s_xpT[cc][r - 1] = v;
    }
    if (tid < 128) s_cw[tid] = P.conv_w[tid];
    if (tid < 32) { s_cb[tid] = P.conv_b[tid]; s_dw[tid] = P.dt_w[tid]; s_db[tid] = P.dt_b[tid]; }
    if (tid < 16) { s_g[tid] = lng[tid]; s_bb[tid] = lnb[tid]; s_gt[tid] = gt[tid]; }
    __syncthreads();

    // ---- gather, element-per-thread
    for (int it = tid; it < nth * 16; it += 256) {
        int tl = it >> 4, k = it & 15;
        int t = t0 - 3 + tl;
        float v;
        if (t < 0) v = 0.f;
        else if (MODE_C >= 0) v = gather_val<(MODE_C >= 0 ? MODE_C : 0)>(x, s_gt, t, k, b, bi, bj);
        else v = gather_rt(mode, x, s_gt, t, k, b, bi, bj);
        s_v[tl][k] = v;
    }
    __syncthreads();

    // ---- layernorm, token-per-thread from LDS
    for (int tl = tid; tl < nth; tl += 256) {
        int t = t0 - 3 + tl;
        if (t < 0) continue;
        float v[16], mu = 0.f;
#pragma unroll
        for (int k = 0; k < 16; k++) { v[k] = s_v[tl][k]; mu += v[k]; }
        mu *= (1.f / 16.f);
        float var = 0.f;
#pragma unroll
        for (int k = 0; k < 16; k++) { float d = v[k] - mu; var += d * d; }
        float inv = rsqrtf(var * (1.f / 16.f) + 1e-5f);
#pragma unroll
        for (int k = 0; k < 16; k++) s_v[tl][k] = (v[k] - mu) * inv * s_g[k] + s_bb[k];
    }
    __syncthreads();

    // ---- VB store (LN output) + in-proj xi half, 4tok x 4oc tiles
    {
        float* vb = VB + ((size_t)n * TLEN + t0) * 16;
        for (int it = tid; it < ntk * 16; it += 256) {
            int j = it >> 4, k = it & 15;
            vb[it] = s_v[j + 3][k];
        }
        const int ntt = (nth + 3) >> 2;
        for (int tl0 = tid; tl0 < ntt * 8; tl0 += 256) {
            int tt = tl0 >> 3, og = tl0 & 7;
            int oc = og * 4;
            float acc[4][4] = {{0.f}};
#pragma unroll
            for (int k = 0; k < 16; k++) {
                float4 wv = *(const float4*)&s_wT[k][oc];
                float a0 = s_v[4 * tt + 0][k];
                float a1 = s_v[4 * tt + 1][k];
                float a2 = s_v[4 * tt + 2][k];
                float a3 = s_v[4 * tt + 3][k];
                acc[0][0] += a0 * wv.x; acc[0][1] += a0 * wv.y; acc[0][2] += a0 * wv.z; acc[0][3] += a0 * wv.w;
                acc[1][0] += a1 * wv.x; acc[1][1] += a1 * wv.y; acc[1][2] += a1 * wv.z; acc[1][3] += a1 * wv.w;
                acc[2][0] += a2 * wv.x; acc[2][1] += a2 * wv.y; acc[2][2] += a2 * wv.z; acc[2][3] += a2 * wv.w;
                acc[3][0] += a3 * wv.x; acc[3][1] += a3 * wv.y; acc[3][2] += a3 * wv.z; acc[3][3] += a3 * wv.w;
            }
#pragma unroll
            for (int i = 0; i < 4; i++) {
                int tl = 4 * tt + i;
                if (tl >= nth) break;
                *(float4*)&s_xi[tl][oc] =
                    make_float4(acc[i][0], acc[i][1], acc[i][2], acc[i][3]);
            }
        }
    }
    __syncthreads();  // s_v dead; pool becomes s_xc

    // ---- conv4 + silu; emit xc to global inline
    {
        int cc = tid & 31, jg = tid >> 5;
        float c0 = s_cw[cc * 4 + 0], c1 = s_cw[cc * 4 + 1];
        float c2 = s_cw[cc * 4 + 2], c3 = s_cw[cc * 4 + 3];
        float cb = s_cb[cc];
        float* scb = sc + ((size_t)n * TLEN + t0) * 96;
        for (int j = jg; j < ntk; j += 8) {
            float acc = 0.f;
            acc += c0 * s_xi[j + 0][cc];
            acc += c1 * s_xi[j + 1][cc];
            acc += c2 * s_xi[j + 2][cc];
            acc += c3 * s_xi[j + 3][cc];
            float v = siluf(acc + cb);
            s_xc[j][cc] = v;
            scb[j * 96 + cc] = v;
        }
    }
    __syncthreads();

    // ---- x-proj B/C rows, 4-token x 4-q register tile
    {
        int qt = tid & 7, tt = tid >> 3;
        if (4 * tt < ntk) {
            float acc[4][4] = {{0.f}};
#pragma unroll
            for (int cc = 0; cc < 32; cc++) {
                float4 wv = *(const float4*)&s_xpT[cc][4 * qt];
                float a0 = s_xc[4 * tt + 0][cc];
                float a1 = s_xc[4 * tt + 1][cc];
                float a2 = s_xc[4 * tt + 2][cc];
                float a3 = s_xc[4 * tt + 3][cc];
                acc[0][0] += a0 * wv.x; acc[0][1] += a0 * wv.y; acc[0][2] += a0 * wv.z; acc[0][3] += a0 * wv.w;
                acc[1][0] += a1 * wv.x; acc[1][1] += a1 * wv.y; acc[1][2] += a1 * wv.z; acc[1][3] += a1 * wv.w;
                acc[2][0] += a2 * wv.x; acc[2][1] += a2 * wv.y; acc[2][2] += a2 * wv.z; acc[2][3] += a2 * wv.w;
                acc[3][0] += a3 * wv.x; acc[3][1] += a3 * wv.y; acc[3][2] += a3 * wv.z; acc[3][3] += a3 * wv.w;
            }
#pragma unroll
            for (int i = 0; i < 4; i++) {
                int j = 4 * tt + i;
                if (j < ntk)
                    *(float4*)&sc[((size_t)n * TLEN + t0 + j) * 96 + 64 + 4 * qt] =
                        make_float4(acc[i][0], acc[i][1], acc[i][2], acc[i][3]);
            }
        }
        if (tid < ntk) {
            float acc = 0.f;
#pragma unroll
            for (int cc = 0; cc < 32; cc++) acc += s_xc[tid][cc] * s_xp0[cc];
            s_dt0[tid] = acc;
        }
    }
    __syncthreads();

    // ---- dt block emit
    {
        float* scb = sc + ((size_t)n * TLEN + t0) * 96;
        for (int it = tid; it < ntk * 32; it += 256) {
            int j = it >> 5, d = it & 31;
            scb[j * 96 + 32 + d] = softplusf(s_dt0[j] * s_dw[d] + s_db[d]);
        }
    }
}

// -------- phase 2a: per-chunk scan summaries; stage only xc/dt/B (80 f) -----
template <int MODE_C, int CHUNKT, int NCHT>
__global__ __launch_bounds__(128) void k_scan1(
    const float* __restrict__ SC0, MP P0, MP P1, int mode_base,
    float* __restrict__ PS0, float* __restrict__ FS0, size_t arena)
{
    const int mode = (MODE_C >= 0) ? MODE_C : (mode_base + (int)blockIdx.y);
    const float* A_log = (mode == 0) ? P0.A_log : P1.A_log;
    const float* sc = SC0 + (size_t)blockIdx.y * arena;
    float* Psum = PS0 + (size_t)blockIdx.y * arena;
    float* Fsum = FS0 + (size_t)blockIdx.y * arena;

    int n = blockIdx.x / NCHT;
    int c = blockIdx.x % NCHT;
    int t0 = c * CHUNKT;
    int nt = min(CHUNKT, TLEN - t0);
    __shared__ __align__(16) float s_sc[CHUNKT * 80];   // xc[32] dt[32] B[16]
    const float* src = sc + ((size_t)n * TLEN + t0) * 96;
    for (int i = threadIdx.x; i < nt * 20; i += 128) {
        int row = i / 20, q = i - row * 20;
        ((float4*)s_sc)[row * 20 + q] = *(const float4*)&src[row * 96 + q * 4];
    }
    int tid = threadIdx.x, d = tid >> 2, sg = tid & 3;
    float4 Av = *(const float4*)&A_log[d * 16 + sg * 4];
    float A0 = -__expf(Av.x), A1 = -__expf(Av.y), A2 = -__expf(Av.z), A3 = -__expf(Av.w);
    __syncthreads();
    float h0 = 0.f, h1 = 0.f, h2 = 0.f, h3 = 0.f;
    float P0v = 1.f, P1v = 1.f, P2v = 1.f, P3v = 1.f;
    for (int t = 0; t < nt; t++) {
        const float* p = s_sc + t * 80;
        float dt = p[32 + d], xc = p[d];
        float4 Bv = *(const float4*)&p[64 + sg * 4];
        float a0 = __expf(dt * A0); h0 = a0 * h0 + dt * Bv.x * xc; P0v *= a0;
        float a1 = __expf(dt * A1); h1 = a1 * h1 + dt * Bv.y * xc; P1v *= a1;
        float a2 = __expf(dt * A2); h2 = a2 * h2 + dt * Bv.z * xc; P2v *= a2;
        float a3 = __expf(dt * A3); h3 = a3 * h3 + dt * Bv.w * xc; P3v *= a3;
    }
    size_t base = ((size_t)n * NCHT + c) * 512 + d * 16 + sg * 4;
    *(float4*)&Psum[base] = make_float4(P0v, P1v, P2v, P3v);
    *(float4*)&Fsum[base] = make_float4(h0, h1, h2, h3);
}

// -------- phase 2b: combine chunk summaries -> incoming state per chunk -----
template <int NCHT>
__global__ __launch_bounds__(512) void k_comb(
    const float* __restrict__ PS0, const float* __restrict__ FS0,
    float* __restrict__ HI0, size_t arena)
{
    const float* Psum = PS0 + (size_t)blockIdx.y * arena;
    const float* Fsum = FS0 + (size_t)blockIdx.y * arena;
    float* Hin = HI0 + (size_t)blockIdx.y * arena;
    int n = blockIdx.x, tid = threadIdx.x;
    const float* pb = Psum + (size_t)n * NCHT * 512;
    const float* fb = Fsum + (size_t)n * NCHT * 512;
    float* hb = Hin + (size_t)n * NCHT * 512;
    float H = 0.f;
#pragma unroll
    for (int c = 0; c < NCHT; c++) {
        float P = pb[(size_t)c * 512 + tid];
        float F = fb[(size_t)c * 512 + tid];
        hb[(size_t)c * 512 + tid] = H;
        H = F + P * H;
    }
}

// --- phase 2c: scan pass 2; y overwrites staged xc slot in LDS, then SC -----
template <int MODE_C, int CHUNKT, int NCHT>
__global__ __launch_bounds__(128) void k_scan2(
    float* __restrict__ SC0, MP P0, MP P1, int mode_base,
    const float* __restrict__ HI0, size_t arena)
{
    const int mode = (MODE_C >= 0) ? MODE_C : (mode_base + (int)blockIdx.y);
    const float* A_log = (mode == 0) ? P0.A_log : P1.A_log;
    const float* Dp = (mode == 0) ? P0.D : P1.D;
    float* sc = SC0 + (size_t)blockIdx.y * arena;
    const float* Hin = HI0 + (size_t)blockIdx.y * arena;

    int n = blockIdx.x / NCHT;
    int c = blockIdx.x % NCHT;
    int t0 = c * CHUNKT;
    int nt = min(CHUNKT, TLEN - t0);
    __shared__ __align__(16) float s_sc[CHUNKT * 96];
    const float* src = sc + ((size_t)n * TLEN + t0) * 96;
    int nv4 = nt * 24;
    for (int i = threadIdx.x; i < nv4; i += 128)
        ((float4*)s_sc)[i] = ((const float4*)src)[i];
    int tid = threadIdx.x, d = tid >> 2, sg = tid & 3;
    float4 Av = *(const float4*)&A_log[d * 16 + sg * 4];
    float A0 = -__expf(Av.x), A1 = -__expf(Av.y), A2 = -__expf(Av.z), A3 = -__expf(Av.w);
    float Dd = Dp[d];
    float4 Hv = *(const float4*)&Hin[((size_t)n * NCHT + c) * 512 + d * 16 + sg * 4];
    float h0 = Hv.x, h1 = Hv.y, h2 = Hv.z, h3 = Hv.w;
    __syncthreads();
    for (int t = 0; t < nt; t++) {
        float* p = s_sc + t * 96;
        float dt = p[32 + d], xc = p[d];
        float4 Bv = *(const float4*)&p[64 + sg * 4];
        float4 Cv = *(const float4*)&p[80 + sg * 4];
        float a0 = __expf(dt * A0); h0 = a0 * h0 + dt * Bv.x * xc;
        float a1 = __expf(dt * A1); h1 = a1 * h1 + dt * Bv.y * xc;
        float a2 = __expf(dt * A2); h2 = a2 * h2 + dt * Bv.z * xc;
        float a3 = __expf(dt * A3); h3 = a3 * h3 + dt * Bv.w * xc;
        float pp = h0 * Cv.x + h1 * Cv.y + h2 * Cv.z + h3 * Cv.w;
        pp += __shfl_xor(pp, 1);
        pp += __shfl_xor(pp, 2);
        if (sg == 0) p[d] = pp + Dd * xc;
    }
    __syncthreads();
    float* yb = sc + ((size_t)n * TLEN + t0) * 96;
    for (int i = threadIdx.x; i < nt * 8; i += 128) {
        int j = i >> 3, q = i & 7;
        *(float4*)&yb[j * 96 + q * 4] = *(const float4*)&s_sc[j * 96 + q * 4];
    }
}

// -------- phase 3: z from VB + gate + out-proj + scatter (per-mode) ---------
template <int MODE>
__global__ void k_p3(const float* __restrict__ ysc, const float* __restrict__ VB,
                     const float* __restrict__ in_w,   // (64,16), rows 32..63 = z
                     const float* __restrict__ out_w,  // (16,32)
                     float* __restrict__ out)
{
    __shared__ float s_w[16 * 32];
    __shared__ float s_wz[16][32];
    for (int i = threadIdx.x; i < 512; i += blockDim.x) {
        s_w[i] = out_w[i];
        int oc = i >> 4, k = i & 15;
        s_wz[k][oc] = in_w[(32 + oc) * 16 + k];
    }
    __syncthreads();
    int tid = blockIdx.x * blockDim.x + threadIdx.x;
    if (tid >= NSEQ * LSEQ) return;
    int n = tid >> 10, l = tid & 1023, t = l + 1;
    const float* y = ysc + ((size_t)n * TLEN + t) * 96;
    const float* vv = VB + ((size_t)n * TLEN + t) * 16;
    float v[16];
#pragma unroll
    for (int k = 0; k < 16; k++) v[k] = vv[k];
    float yv[32];
#pragma unroll
    for (int c = 0; c < 32; c++) {
        float z = 0.f;
#pragma unroll
        for (int k = 0; k < 16; k++) z += v[k] * s_wz[k][c];
        yv[c] = y[c] * siluf(z);
    }
    float o[16];
#pragma unroll
    for (int j = 0; j < 16; j++) {
        float acc = 0.f;
#pragma unroll
        for (int c = 0; c < 32; c++) acc += yv[c] * s_w[j * 32 + c];
        o[j] = acc * (1.0f / 3.0f);
    }
    int b = n >> 6, cube = n & 63;
    if (MODE == 0) {
        int i2 = l >> 5, j2 = l & 31;
        int io = i2 >> 1, jo = j2 >> 1;
        int coff = ((i2 & 1) << 1) | (j2 & 1);
#pragma unroll
        for (int j = 0; j < 16; j++) out[oidx(b, cube, j * 4 + coff, io, jo)] = o[j];
    } else if (MODE == 1) {
        int c = l >> 4, jj = l & 15;
#pragma unroll
        for (int j = 0; j < 16; j++) out[oidx(b, cube, c, j, jj)] += o[j];
    } else {
        int c = l >> 4, ii = l & 15;
#pragma unroll
        for (int j = 0; j < 16; j++) out[oidx(b, cube, c, ii, j)] += o[j];
    }
}

}  // namespace

extern "C" void kernel_launch(void* const* d_in, const int* in_sizes, int n_in,
                              void* d_out, int out_size, void* d_ws, size_t ws_size,
                              hipStream_t stream) {
    const float* x   = (const float*)d_in[0];
    const float* gt1 = (const float*)d_in[1];
    const float* gt2 = (const float*)d_in[2];
    const float* ln1g = (const float*)d_in[3];
    const float* ln1b = (const float*)d_in[4];
    const float* ln2g = (const float*)d_in[5];
    const float* ln2b = (const float*)d_in[6];
    MP P[2];
    for (int mi = 0; mi < 2; mi++) {
        P[mi].in_w   = (const float*)d_in[7 + mi * 9 + 0];
        P[mi].conv_w = (const float*)d_in[7 + mi * 9 + 1];
        P[mi].conv_b = (const float*)d_in[7 + mi * 9 + 2];
        P[mi].xproj_w= (const float*)d_in[7 + mi * 9 + 3];
        P[mi].dt_w   = (const float*)d_in[7 + mi * 9 + 4];
        P[mi].dt_b   = (const float*)d_in[7 + mi * 9 + 5];
        P[mi].A_log  = (const float*)d_in[7 + mi * 9 + 6];
        P[mi].D      = (const float*)d_in[7 + mi * 9 + 7];
        P[mi].out_w  = (const float*)d_in[7 + mi * 9 + 8];
    }
    float* out = (float*)d_out;

    const size_t VBs = (size_t)NSEQ * TLEN * 16;
    const size_t SCs = (size_t)NSEQ * TLEN * 96;
    const size_t PS16 = (size_t)NSEQ * 16 * 512;
    const size_t PS32 = (size_t)NSEQ * 32 * 512;
    const size_t arena16 = VBs + SCs + 3 * PS16;   // 71.4 MB
    const size_t arena32 = VBs + SCs + 3 * PS32;   // 84.0 MB

    float* A0 = (float*)d_ws;
    dim3 b256(256), b128(128), b512(512);
    dim3 grd3((NSEQ * LSEQ + 255) / 256);

    const bool fits3_32 = ws_size >= 3 * arena32 * sizeof(float);
    const bool fits3_16 = ws_size >= 3 * arena16 * sizeof(float);
    const bool fits2_16 = ws_size >= 2 * arena16 * sizeof(float);

    if (fits3_32) {
        const size_t arena = arena32;
        auto VB = [&](int y) { return A0 + (size_t)y * arena; };
        auto SC = [&](int y) { return A0 + (size_t)y * arena + VBs; };
        auto PS = [&](int y) { return A0 + (size_t)y * arena + VBs + SCs; };
        auto FS = [&](int y) { return PS(y) + PS32; };
        auto HI = [&](int y) { return FS(y) + PS32; };
        k_p1<-1><<<dim3(NSEQ * NT, 3), b256, 0, stream>>>(
            x, gt1, gt2, ln1g, ln1b, ln2g, ln2b, P[0], P[1], 0, VB(0), SC(0), arena);
        k_scan1<-1, 33, 32><<<dim3(NSEQ * 32, 3), b128, 0, stream>>>(
            SC(0), P[0], P[1], 0, PS(0), FS(0), arena);
        k_comb<32><<<dim3(NSEQ, 3), b512, 0, stream>>>(PS(0), FS(0), HI(0), arena);
        k_scan2<-1, 33, 32><<<dim3(NSEQ * 32, 3), b128, 0, stream>>>(
            SC(0), P[0], P[1], 0, HI(0), arena);
        k_p3<0><<<grd3, b256, 0, stream>>>(SC(0), VB(0), P[0].in_w, P[0].out_w, out);
        k_p3<1><<<grd3, b256, 0, stream>>>(SC(1), VB(1), P[1].in_w, P[1].out_w, out);
        k_p3<2><<<grd3, b256, 0, stream>>>(SC(2), VB(2), P[1].in_w, P[1].out_w, out);
    } else if (fits3_16) {
        const size_t arena = arena16;
        auto VB = [&](int y) { return A0 + (size_t)y * arena; };
        auto SC = [&](int y) { return A0 + (size_t)y * arena + VBs; };
        auto PS = [&](int y) { return A0 + (size_t)y * arena + VBs + SCs; };
        auto FS = [&](int y) { return PS(y) + PS16; };
        auto HI = [&](int y) { return FS(y) + PS16; };
        k_p1<-1><<<dim3(NSEQ * NT, 3), b256, 0, stream>>>(
            x, gt1, gt2, ln1g, ln1b, ln2g, ln2b, P[0], P[1], 0, VB(0), SC(0), arena);
        k_scan1<-1, 65, 16><<<dim3(NSEQ * 16, 3), b128, 0, stream>>>(
            SC(0), P[0], P[1], 0, PS(0), FS(0), arena);
        k_comb<16><<<dim3(NSEQ, 3), b512, 0, stream>>>(PS(0), FS(0), HI(0), arena);
        k_scan2<-1, 65, 16><<<dim3(NSEQ * 16, 3), b128, 0, stream>>>(
            SC(0), P[0], P[1], 0, HI(0), arena);
        k_p3<0><<<grd3, b256, 0, stream>>>(SC(0), VB(0), P[0].in_w, P[0].out_w, out);
        k_p3<1><<<grd3, b256, 0, stream>>>(SC(1), VB(1), P[1].in_w, P[1].out_w, out);
        k_p3<2><<<grd3, b256, 0, stream>>>(SC(2), VB(2), P[1].in_w, P[1].out_w, out);
    } else if (fits2_16) {
        const size_t arena = arena16;
        auto VB = [&](int y) { return A0 + (size_t)y * arena; };
        auto SC = [&](int y) { return A0 + (size_t)y * arena + VBs; };
        auto PS = [&](int y) { return A0 + (size_t)y * arena + VBs + SCs; };
        auto FS = [&](int y) { return PS(y) + PS16; };
        auto HI = [&](int y) { return FS(y) + PS16; };
        k_p1<0><<<dim3(NSEQ * NT, 1), b256, 0, stream>>>(
            x, gt1, gt2, ln1g, ln1b, ln2g, ln2b, P[0], P[1], 0, VB(0), SC(0), arena);
        k_scan1<0, 65, 16><<<dim3(NSEQ * 16, 1), b128, 0, stream>>>(
            SC(0), P[0], P[1], 0, PS(0), FS(0), arena);
        k_comb<16><<<dim3(NSEQ, 1), b512, 0, stream>>>(PS(0), FS(0), HI(0), arena);
        k_scan2<0, 65, 16><<<dim3(NSEQ * 16, 1), b128, 0, stream>>>(
            SC(0), P[0], P[1], 0, HI(0), arena);
        k_p3<0><<<grd3, b256, 0, stream>>>(SC(0), VB(0), P[0].in_w, P[0].out_w, out);
        k_p1<-1><<<dim3(NSEQ * NT, 2), b256, 0, stream>>>(
            x, gt1, gt2, ln1g, ln1b, ln2g, ln2b, P[0], P[1], 1, VB(0), SC(0), arena);
        k_scan1<-1, 65, 16><<<dim3(NSEQ * 16, 2), b128, 0, stream>>>(
            SC(0), P[0], P[1], 1, PS(0), FS(0), arena);
        k_comb<16><<<dim3(NSEQ, 2), b512, 0, stream>>>(PS(0), FS(0), HI(0), arena);
        k_scan2<-1, 65, 16><<<dim3(NSEQ * 16, 2), b128, 0, stream>>>(
            SC(0), P[0], P[1], 1, HI(0), arena);
        k_p3<1><<<grd3, b256, 0, stream>>>(SC(0), VB(0), P[1].in_w, P[1].out_w, out);
        k_p3<2><<<grd3, b256, 0, stream>>>(SC(1), VB(1), P[1].in_w, P[1].out_w, out);
    } else {
        const size_t arena = arena16;
        auto VB = [&](int y) { return A0 + (size_t)y * arena; };
        auto SC = [&](int y) { return A0 + (size_t)y * arena + VBs; };
        auto PS = [&](int y) { return A0 + (size_t)y * arena + VBs + SCs; };
        auto FS = [&](int y) { return PS(y) + PS16; };
        auto HI = [&](int y) { return FS(y) + PS16; };
        for (int mode = 0; mode < 3; mode++) {
            if (mode == 0)
                k_p1<0><<<dim3(NSEQ * NT, 1), b256, 0, stream>>>(
                    x, gt1, gt2, ln1g, ln1b, ln2g, ln2b, P[0], P[1], 0, VB(0), SC(0), arena);
            else if (mode == 1)
                k_p1<1><<<dim3(NSEQ * NT, 1), b256, 0, stream>>>(
                    x, gt1, gt2, ln1g, ln1b, ln2g, ln2b, P[0], P[1], 0, VB(0), SC(0), arena);
            else
                k_p1<2><<<dim3(NSEQ * NT, 1), b256, 0, stream>>>(
                    x, gt1, gt2, ln1g, ln1b, ln2g, ln2b, P[0], P[1], 0, VB(0), SC(0), arena);
            if (mode == 0)
                k_scan1<0, 65, 16><<<dim3(NSEQ * 16, 1), b128, 0, stream>>>(SC(0), P[0], P[1], 0, PS(0), FS(0), arena);
            else if (mode == 1)
                k_scan1<1, 65, 16><<<dim3(NSEQ * 16, 1), b128, 0, stream>>>(SC(0), P[0], P[1], 0, PS(0), FS(0), arena);
            else
                k_scan1<2, 65, 16><<<dim3(NSEQ * 16, 1), b128, 0, stream>>>(SC(0), P[0], P[1], 0, PS(0), FS(0), arena);
            k_comb<16><<<dim3(NSEQ, 1), b512, 0, stream>>>(PS(0), FS(0), HI(0), arena);
            if (mode == 0)
                k_scan2<0, 65, 16><<<dim3(NSEQ * 16, 1), b128, 0, stream>>>(SC(0), P[0], P[1], 0, HI(0), arena);
            else if (mode == 1)
                k_scan2<1, 65, 16><<<dim3(NSEQ * 16, 1), b128, 0, stream>>>(SC(0), P[0], P[1], 0, HI(0), arena);
            else
                k_scan2<2, 65, 16><<<dim3(NSEQ * 16, 1), b128, 0, stream>>>(SC(0), P[0], P[1], 0, HI(0), arena);
            if (mode == 0)      k_p3<0><<<grd3, b256, 0, stream>>>(SC(0), VB(0), P[0].in_w, P[0].out_w, out);
            else if (mode == 1) k_p3<1><<<grd3, b256, 0, stream>>>(SC(0), VB(0), P[1].in_w, P[1].out_w, out);
            else                k_p3<2><<<grd3, b256, 0, stream>>>(SC(0), VB(0), P[1].in_w, P[1].out_w, out);
        }
    }
}